// Round 4
// baseline (521.977 us; speedup 1.0000x reference)
//
#include <hip/hip_runtime.h>
#include <hip/hip_bf16.h>

// ---------------------------------------------------------------------------
// GumbelNeRF fused kernel, round 4: transposed pass 1 + 3 blocks/CU.
//
// vs round 3 (240us main, MfmaUtil 22%, VALU 36%, occ 21.7%):
//  - Pass 1 computes S^T = W_sh^T @ y^T (MFMA operand swap; A and B frags
//    have identical lane maps, so the ws layout is unchanged). Points land
//    in C columns, h-features in rows -> the w_sig dot becomes an IN-LANE
//    fma reduction (psum[nt]) + 4 b32 LDS writes per expert. The DPP
//    rowsum tree + cndmask select (~140 VALU ops/expert) are eliminated.
//  - One barrier per expert (argmax update fused, t<64), 8 in pass 1 vs
//    round 2's 24; the barrier body is tiny (16 adds + softplus).
//  - LDS 54784 -> 46656 B (sRed [64][20], sVD dropped — viewdir PE is
//    recomputed straight into sSB during pass 2a) => 3 blocks/CU.
//  - lo y-frags not hoisted (64 VGPRs freed): re-read from sYl via
//    ds_read_b128 in the expert loop (LDS pipe is idle).
//    __launch_bounds__(256,3) caps unified regs for 3 waves/SIMD.
// Sigma/score numerics: same f16 3-product split (hi + lo/2048), fp32
// accumulate, same threefry gumbel — only reduction order differs.
// ---------------------------------------------------------------------------

#define NPTS 131072
#define PT 64
#define NTH 256
#define NBLK (NPTS / PT)
#define INV2048 (1.0f / 2048.0f)

// ws sections (f16 element offsets) — identical to rounds 2/3
#define WS_ENC_H 0
#define WS_ENC_L 8192
#define WS_SH_H  16384
#define WS_SH_L  147456
#define WS_R1_H  278528

// LDS byte offsets, total 46656
#define OFF_YH   0      // sYh [64][136] f16 = 17408 ; pass2b+: sH [64][68] f32
#define OFF_B    17408  // sPEh[64][72]+sPEl (18432) | sYl [64][136] | sSB [64][168] f16 (21504)
#define OFF_RED  38912  // sRed [64][20] f32 = 5120 (16 (w,q) partials + pad)
#define OFF_GUM  44032  // sGum [512] f32 = 2048
#define OFF_BID  46080  // i32[64]
#define OFF_LIST 46336  // i32[64] slot->pt
#define OFF_CNT  46592  // i32[8]
#define OFF_OFFS 46624  // i32[8]
#define SMEM_SZ  46656

typedef __attribute__((ext_vector_type(8))) _Float16 f16x8;
typedef __attribute__((ext_vector_type(4))) _Float16 f16x4;
typedef __attribute__((ext_vector_type(4))) float f32x4;

#define MFMA(a, b, c) __builtin_amdgcn_mfma_f32_16x16x32_f16((a), (b), (c), 0, 0, 0)

__device__ __forceinline__ unsigned rotl32(unsigned x, int d) {
  return (x << d) | (x >> (32 - d));
}

// JAX threefry2x32, keys (0,42), counter (0, flat), partitionable fold.
__device__ __forceinline__ float gumbel_for(unsigned flat) {
  const unsigned k0 = 0u, k1 = 42u;
  const unsigned ks2 = k0 ^ k1 ^ 0x1BD11BDAu;
  unsigned x0 = 0u + k0;
  unsigned x1 = flat + k1;
#define TF_RND(r) { x0 += x1; x1 = rotl32(x1, r); x1 ^= x0; }
  TF_RND(13) TF_RND(15) TF_RND(26) TF_RND(6)
  x0 += k1;  x1 += ks2 + 1u;
  TF_RND(17) TF_RND(29) TF_RND(16) TF_RND(24)
  x0 += ks2; x1 += k0 + 2u;
  TF_RND(13) TF_RND(15) TF_RND(26) TF_RND(6)
  x0 += k0;  x1 += k1 + 3u;
  TF_RND(17) TF_RND(29) TF_RND(16) TF_RND(24)
  x0 += k1;  x1 += ks2 + 4u;
  TF_RND(13) TF_RND(15) TF_RND(26) TF_RND(6)
  x0 += ks2; x1 += k0 + 5u;
#undef TF_RND
  unsigned bits = x0 ^ x1;
  float u = __uint_as_float((bits >> 9) | 0x3f800000u) - 1.0f;
  return -logf(-logf(u + 1e-20f) + 1e-20f);
}

// ---------------------------------------------------------------------------
// prep: fp32 weights -> fragment-linear f16 (scaled split) in ws  [unchanged]
// ---------------------------------------------------------------------------
__global__ void prep_kernel(const float* __restrict__ W_enc,
                            const float* __restrict__ W_sh,
                            const float* __restrict__ W_r1,
                            _Float16* __restrict__ ws) {
  int idx = blockIdx.x * 256 + threadIdx.x;
  if (idx < 8192) {
    int tile = idx >> 9, r = idx & 511;
    int L = r >> 3, j = r & 7;
    int nt = tile >> 1, kt = tile & 1;
    int k = kt * 32 + (L >> 4) * 8 + j;
    int n = nt * 16 + (L & 15);
    float v = (k < 63) ? W_enc[k * 128 + n] : 0.0f;
    _Float16 h = (_Float16)v;
    ws[WS_ENC_H + idx] = h;
    ws[WS_ENC_L + idx] = (_Float16)((v - (float)h) * 2048.0f);
  } else if (idx < 8192 + 131072) {
    int s = idx - 8192;
    int tile = s >> 9, r = s & 511;
    int L = r >> 3, j = r & 7;
    int e = tile >> 5, nt = (tile >> 2) & 7, kt = tile & 3;
    int k = kt * 32 + (L >> 4) * 8 + j;
    int n = nt * 16 + (L & 15);
    float v = W_sh[e * 16384 + k * 128 + n];
    _Float16 h = (_Float16)v;
    ws[WS_SH_H + s] = h;
    ws[WS_SH_L + s] = (_Float16)((v - (float)h) * 2048.0f);
  } else if (idx < 8192 + 131072 + 81920) {
    int s = idx - (8192 + 131072);
    int tile = s >> 9, r = s & 511;
    int L = r >> 3, j = r & 7;
    int e = tile / 20, rr = tile % 20;
    int nt = rr / 5, kt = rr % 5;
    int k = kt * 32 + (L >> 4) * 8 + j;
    int n = nt * 16 + (L & 15);
    float v = (k < 155) ? W_r1[e * 9920 + k * 64 + n] : 0.0f;
    ws[WS_R1_H + s] = (_Float16)v;
  }
}

// ---------------------------------------------------------------------------
__global__ __launch_bounds__(NTH, 3)
void nerf_moe_kernel(const float* __restrict__ x,
                     const float* __restrict__ b_enc,
                     const float* __restrict__ b_sh,
                     const float* __restrict__ w_sig, const float* __restrict__ b_sig,
                     const float* __restrict__ b_r1,
                     const float* __restrict__ W_r2,  const float* __restrict__ b_r2,
                     const _Float16* __restrict__ wsw,
                     float* __restrict__ out) {
  __shared__ __align__(16) unsigned char smem[SMEM_SZ];
  _Float16* sYh  = (_Float16*)(smem + OFF_YH);
  float*    sH   = (float*)(smem + OFF_YH);
  _Float16* sYl  = (_Float16*)(smem + OFF_B);
  _Float16* sPEh = (_Float16*)(smem + OFF_B);
  _Float16* sPEl = (_Float16*)(smem + OFF_B + 9216);
  _Float16* sSB  = (_Float16*)(smem + OFF_B);
  float*    sRed = (float*)(smem + OFF_RED);
  float*    sGum = (float*)(smem + OFF_GUM);
  int*      sBid = (int*)(smem + OFF_BID);
  int*      sList = (int*)(smem + OFF_LIST);
  int*      sCnt = (int*)(smem + OFF_CNT);
  int*      sOff = (int*)(smem + OFF_OFFS);
  float*    sBsc = sGum + 448;   // best score f32[64] overlays sGum tail?  NO —
  // sGum[512] fully used. Best score/sigma kept in regs by t<64 lanes of
  // wave 0 across iterations (wave-private, no LDS needed).

  const int t  = threadIdx.x;
  const int w  = t >> 6;        // wave id 0..3
  const int L  = t & 63;        // lane
  const int q  = L >> 4;        // quad 0..3
  const int c  = L & 15;
  const int n0 = blockIdx.x * PT;
  (void)sBsc;

  // ---- phase 0: xyz positional encoding + gumbel precompute ----
  for (int idx = t; idx < PT * 64; idx += NTH) {
    int p = idx >> 6, f = idx & 63;
    const float* xr = x + (size_t)(n0 + p) * 6;
    float v;
    if (f < 3)       v = xr[f];
    else if (f < 33) { int g = f - 3;  v = sinf(xr[g % 3] * (float)(1 << (g / 3))); }
    else if (f < 63) { int g = f - 33; v = cosf(xr[g % 3] * (float)(1 << (g / 3))); }
    else             v = 0.0f;
    _Float16 h = (_Float16)v;
    sPEh[p * 72 + f] = h;
    sPEl[p * 72 + f] = (_Float16)((v - (float)h) * 2048.0f);
  }
  sGum[t]       = gumbel_for((unsigned)(n0 * 8 + t));
  sGum[t + 256] = gumbel_for((unsigned)(n0 * 8 + t + 256));
  __syncthreads();                                   // (1)

  // ---- phase A: Y = relu(PE @ W_enc + b) via MFMA ----
  {
    f16x8 beh[2][2], bel[2][2];
    #pragma unroll
    for (int ntL = 0; ntL < 2; ++ntL)
      #pragma unroll
      for (int kt = 0; kt < 2; ++kt) {
        int tile = (2 * w + ntL) * 2 + kt;
        beh[ntL][kt] = *(const f16x8*)(wsw + WS_ENC_H + tile * 512 + L * 8);
        bel[ntL][kt] = *(const f16x8*)(wsw + WS_ENC_L + tile * 512 + L * 8);
      }
    f16x8 pah[4][2], pal[4][2];
    #pragma unroll
    for (int mt = 0; mt < 4; ++mt)
      #pragma unroll
      for (int kt = 0; kt < 2; ++kt) {
        int off = (mt * 16 + c) * 72 + kt * 32 + q * 8;
        pah[mt][kt] = *(const f16x8*)(sPEh + off);
        pal[mt][kt] = *(const f16x8*)(sPEl + off);
      }
    f32x4 a1[4][2], a2[4][2];
    #pragma unroll
    for (int mt = 0; mt < 4; ++mt)
      #pragma unroll
      for (int ntL = 0; ntL < 2; ++ntL) { a1[mt][ntL] = (f32x4)0.0f; a2[mt][ntL] = (f32x4)0.0f; }
    #pragma unroll
    for (int kt = 0; kt < 2; ++kt)
      #pragma unroll
      for (int mt = 0; mt < 4; ++mt)
        #pragma unroll
        for (int ntL = 0; ntL < 2; ++ntL) {
          a1[mt][ntL] = MFMA(pah[mt][kt], beh[ntL][kt], a1[mt][ntL]);
          a2[mt][ntL] = MFMA(pah[mt][kt], bel[ntL][kt], a2[mt][ntL]);
          a2[mt][ntL] = MFMA(pal[mt][kt], beh[ntL][kt], a2[mt][ntL]);
        }
    __syncthreads();                                 // (2) sPE reads done -> sYl writable
    float bb0 = b_enc[(2 * w) * 16 + c];
    float bb1 = b_enc[(2 * w + 1) * 16 + c];
    #pragma unroll
    for (int mt = 0; mt < 4; ++mt)
      #pragma unroll
      for (int ntL = 0; ntL < 2; ++ntL) {
        float bb = ntL ? bb1 : bb0;
        int col = (2 * w + ntL) * 16 + c;
        #pragma unroll
        for (int r = 0; r < 4; ++r) {
          float v = fmaxf(a1[mt][ntL][r] + a2[mt][ntL][r] * INV2048 + bb, 0.0f);
          int row = mt * 16 + q * 4 + r;
          _Float16 h = (_Float16)v;
          sYh[row * 136 + col] = h;
          sYl[row * 136 + col] = (_Float16)((v - (float)h) * 2048.0f);
        }
      }
  }
  __syncthreads();                                   // (3)

  // hoist Y hi frags (64 VGPR); lo re-read from sYl per use
  f16x8 Ah[4][4];
  #pragma unroll
  for (int nt = 0; nt < 4; ++nt)
    #pragma unroll
    for (int kt = 0; kt < 4; ++kt)
      Ah[nt][kt] = *(const f16x8*)(sYh + (nt * 16 + c) * 136 + kt * 32 + q * 8);
  const f32x4 wsv0 = *(const f32x4*)(w_sig + (2 * w) * 16 + q * 4);
  const f32x4 wsv1 = *(const f32x4*)(w_sig + (2 * w + 1) * 16 + q * 4);
  const float bs = b_sig[0];

  // running argmax state (live only in t<64 lanes)
  float best = 0.0f, bsig = 0.0f;
  int bide = 0;

  // ---- pass 1: 8 experts, transposed S^T, 1 barrier/expert ----
  #pragma unroll 1
  for (int e = 0; e < 8; ++e) {
    float psum[4] = {0.f, 0.f, 0.f, 0.f};
    #pragma unroll
    for (int i = 0; i < 2; ++i) {                    // h-tile 2w+i
      f32x4 a1[4], a2[4];
      #pragma unroll
      for (int nt = 0; nt < 4; ++nt) { a1[nt] = (f32x4)0.0f; a2[nt] = (f32x4)0.0f; }
      #pragma unroll
      for (int kt = 0; kt < 4; ++kt) {
        int tile = (e * 8 + 2 * w + i) * 4 + kt;
        f16x8 bh = *(const f16x8*)(wsw + WS_SH_H + tile * 512 + L * 8);
        f16x8 bl = *(const f16x8*)(wsw + WS_SH_L + tile * 512 + L * 8);
        #pragma unroll
        for (int nt = 0; nt < 4; ++nt) {
          f16x8 al = *(const f16x8*)(sYl + (nt * 16 + c) * 136 + kt * 32 + q * 8);
          a1[nt] = MFMA(bh, Ah[nt][kt], a1[nt]);
          a2[nt] = MFMA(bl, Ah[nt][kt], a2[nt]);
          a2[nt] = MFMA(bh, al, a2[nt]);
        }
      }
      f32x4 bb = *(const f32x4*)(b_sh + e * 128 + (2 * w + i) * 16 + q * 4);
      f32x4 wv = i ? wsv1 : wsv0;
      #pragma unroll
      for (int nt = 0; nt < 4; ++nt)
        #pragma unroll
        for (int r = 0; r < 4; ++r) {
          float s = fmaxf(fmaf(a2[nt][r], INV2048, a1[nt][r]) + bb[r], 0.0f);
          psum[nt] = fmaf(s, wv[r], psum[nt]);
        }
    }
    #pragma unroll
    for (int nt = 0; nt < 4; ++nt)
      sRed[(nt * 16 + c) * 20 + w * 4 + q] = psum[nt];
    __syncthreads();                                 // (expert barrier)
    if (t < PT) {
      const f32x4* rp = (const f32x4*)(sRed + t * 20);
      f32x4 p0 = rp[0], p1 = rp[1], p2 = rp[2], p3 = rp[3];
      float s = ((p0.x + p0.y) + (p0.z + p0.w)) + ((p1.x + p1.y) + (p1.z + p1.w)) +
                ((p2.x + p2.y) + (p2.z + p2.w)) + ((p3.x + p3.y) + (p3.z + p3.w));
      float dotv = s + bs;
      float sig = fmaxf(dotv, 0.0f) + log1pf(expf(-fabsf(dotv)));
      float z = logf(sig + 1e-10f) / 0.166667f;
      float score = z + sGum[t * 8 + e];
      if (e == 0 || score > best) { best = score; bsig = sig; bide = e; }
    }
    // no second barrier: next expert's sRed writes only follow this
    // barrier after all waves pass it on the NEXT iteration's barrier —
    // but writes for e+1 could race t<64 reads of e. One more barrier:
    __syncthreads();                                 // (expert barrier 2)
  }
  if (t < PT) {
    sBid[t] = bide;
    out[(size_t)(n0 + t) * 4 + 3] = bsig;
  }
  __syncthreads();                                   // (4)

  // ---- bucket lists ----
  if (t < 8) {
    int cnt = 0;
    for (int p = 0; p < PT; ++p) cnt += (sBid[p] == t);
    sCnt[t] = cnt;
  }
  __syncthreads();                                   // (5)
  if (t < 8) {
    int off = 0;
    for (int i = 0; i < t; ++i) off += sCnt[i];
    sOff[t] = off;
    int k = off;
    for (int p = 0; p < PT; ++p) if (sBid[p] == t) sList[k++] = p;
  }
  __syncthreads();                                   // (6)

  // ---- pass 2a: viewdir PE into sSB + winner S recompute (transposed) ----
  for (int idx = t; idx < PT * 32; idx += NTH) {
    int s = idx >> 5, cc = idx & 31;
    int pt = sList[s];
    const float* xr = x + (size_t)(n0 + pt) * 6 + 3;
    float v;
    if (cc < 3)       v = xr[cc];
    else if (cc < 15) { int g = cc - 3;  v = sinf(xr[g % 3] * (float)(1 << (g / 3))); }
    else if (cc < 27) { int g = cc - 15; v = cosf(xr[g % 3] * (float)(1 << (g / 3))); }
    else              v = 0.0f;
    sSB[s * 168 + 128 + cc] = (_Float16)v;
  }
  #pragma unroll 1
  for (int ei = 0; ei < 2; ++ei) {
    int e = 2 * w + ei;
    int cnt = sCnt[e], off = sOff[e];
    for (int base = 0; base < cnt; base += 16) {
      int sidx = base + c; if (sidx >= cnt) sidx = cnt - 1;
      int pt = sList[off + sidx];
      f16x8 yb[4];
      #pragma unroll
      for (int kt = 0; kt < 4; ++kt)
        yb[kt] = *(const f16x8*)(sYh + pt * 136 + kt * 32 + q * 8);
      f32x4 acc[8];
      #pragma unroll
      for (int jt = 0; jt < 8; ++jt) acc[jt] = (f32x4)0.0f;
      #pragma unroll
      for (int jt = 0; jt < 8; ++jt)
        #pragma unroll
        for (int kt = 0; kt < 4; ++kt) {
          f16x8 a = *(const f16x8*)(wsw + WS_SH_H + ((e * 8 + jt) * 4 + kt) * 512 + L * 8);
          acc[jt] = MFMA(a, yb[kt], acc[jt]);
        }
      bool wr = (base + c) < cnt;
      int slot = off + base + c;
      #pragma unroll
      for (int jt = 0; jt < 8; ++jt) {
        f32x4 bb = *(const f32x4*)(b_sh + e * 128 + jt * 16 + q * 4);
        f16x4 v;
        #pragma unroll
        for (int r = 0; r < 4; ++r)
          v[r] = (_Float16)fmaxf(acc[jt][r] + bb[r], 0.0f);
        if (wr) *(f16x4*)(sSB + slot * 168 + jt * 16 + q * 4) = v;
      }
    }
  }
  __syncthreads();                                   // (7) sYh dead -> sH writable

  // ---- pass 2b: rgb layer 1 via MFMA ([S;vd] @ W_r1) ----
  #pragma unroll 1
  for (int ei = 0; ei < 2; ++ei) {
    int e = 2 * w + ei;
    int cnt = sCnt[e], off = sOff[e];
    for (int base = 0; base < cnt; base += 16) {
      int sidx = base + c; if (sidx >= cnt) sidx = cnt - 1;
      int slot = off + sidx;
      f16x8 ag[5];
      #pragma unroll
      for (int kt = 0; kt < 5; ++kt)
        ag[kt] = *(const f16x8*)(sSB + slot * 168 + kt * 32 + q * 8);
      f32x4 hacc[4];
      #pragma unroll
      for (int nt = 0; nt < 4; ++nt) hacc[nt] = (f32x4)0.0f;
      #pragma unroll
      for (int nt = 0; nt < 4; ++nt)
        #pragma unroll
        for (int kt = 0; kt < 5; ++kt) {
          f16x8 bf = *(const f16x8*)(wsw + WS_R1_H + ((e * 4 + nt) * 5 + kt) * 512 + L * 8);
          hacc[nt] = MFMA(ag[kt], bf, hacc[nt]);
        }
      #pragma unroll
      for (int nt = 0; nt < 4; ++nt) {
        float bb = b_r1[e * 64 + nt * 16 + c];
        #pragma unroll
        for (int r = 0; r < 4; ++r) {
          int m = q * 4 + r;
          if (base + m < cnt)
            sH[(off + base + m) * 68 + nt * 16 + c] = fmaxf(hacc[nt][r] + bb, 0.0f);
        }
      }
    }
  }
  __syncthreads();                                   // (8)

  // ---- layer 2: rgb = sigmoid(h @ W_r2 + b) ----
  if (t < 192) {
    int s = t / 3, o = t - s * 3;
    int pt = sList[s];
    int e = sBid[pt];
    float a = b_r2[e * 3 + o];
    const float* w2 = W_r2 + e * 192 + o;
    #pragma unroll
    for (int jj = 0; jj < 64; jj += 4) {
      f32x4 h4 = *(const f32x4*)(sH + s * 68 + jj);
      a = fmaf(h4.x, w2[jj * 3], a);
      a = fmaf(h4.y, w2[jj * 3 + 3], a);
      a = fmaf(h4.z, w2[jj * 3 + 6], a);
      a = fmaf(h4.w, w2[jj * 3 + 9], a);
    }
    out[(size_t)(n0 + pt) * 4 + o] = 1.0f / (1.0f + expf(-a));
  }
}

extern "C" void kernel_launch(void* const* d_in, const int* in_sizes, int n_in,
                              void* d_out, int out_size, void* d_ws, size_t ws_size,
                              hipStream_t stream) {
  (void)in_sizes; (void)n_in; (void)ws_size; (void)out_size;
  const float* x     = (const float*)d_in[0];
  const float* W_enc = (const float*)d_in[1];
  const float* b_enc = (const float*)d_in[2];
  const float* W_sh  = (const float*)d_in[3];
  const float* b_sh  = (const float*)d_in[4];
  const float* w_sig = (const float*)d_in[5];
  const float* b_sig = (const float*)d_in[6];
  const float* W_r1  = (const float*)d_in[7];
  const float* b_r1  = (const float*)d_in[8];
  const float* W_r2  = (const float*)d_in[9];
  const float* b_r2  = (const float*)d_in[10];
  _Float16* ws = (_Float16*)d_ws;     // needs 720896 B
  float* outp = (float*)d_out;
  prep_kernel<<<864, 256, 0, stream>>>(W_enc, W_sh, W_r1, ws);
  nerf_moe_kernel<<<NBLK, NTH, 0, stream>>>(x, b_enc, b_sh, w_sig, b_sig,
                                            b_r1, W_r2, b_r2, ws, outp);
}

// Round 5
// 279.208 us; speedup vs baseline: 1.8695x; 1.8695x over previous
//
#include <hip/hip_runtime.h>
#include <hip/hip_bf16.h>

// ---------------------------------------------------------------------------
// GumbelNeRF fused kernel, round 5: transposed pass 1, zero-barrier via
// shfl-reduced per-expert slots, sane register pressure.
//
// Round-4 post-mortem: __launch_bounds__(256,3) capped unified VGPR+AGPR at
// ~170 -> compiler split arch=84 and spilled the MFMA working set: 1.15 GB
// scratch traffic/dispatch = the whole 477us. Fix: bounds (256,2) (rounds
// 2-3 proven 128 VGPR, no spill); occupancy comes from LDS instead
// (49856 B -> 3 blocks/CU).
//
// Pass 1 (transposed S^T = W_sh^T @ y^T, per-expert):
//   - in-lane w_sig fma into psum[4] (points in C columns)
//   - quad-reduction IN-REGISTER: psum += shfl_xor(16) + shfl_xor(32)
//   - q==0 lanes write per-wave partial to sRedE[e][w][pt] (8x4x65 f32)
//   -> ZERO barriers across all 8 experts; one barrier + single argmax after.
// Sigma numerics: f16 3-product split (hi + lo/2048), fp32 accumulate,
// threefry gumbel — same as passing rounds 2-4.
// ---------------------------------------------------------------------------

#define NPTS 131072
#define PT 64
#define NTH 256
#define NBLK (NPTS / PT)
#define INV2048 (1.0f / 2048.0f)

// ws sections (f16 element offsets) — identical to rounds 2-4
#define WS_ENC_H 0
#define WS_ENC_L 8192
#define WS_SH_H  16384
#define WS_SH_L  147456
#define WS_R1_H  278528

// LDS byte offsets, total 49856
#define OFF_YH   0      // sYh [64][136] f16 = 17408 ; pass2b+: sH [64][68] f32
#define OFF_B    17408  // sPEh[64][72]+sPEl (18432) | sYl [64][136] | sSB [64][168] f16 (21504)
#define OFF_RED  38912  // sRedE [8][4][65] f32 = 8320
#define OFF_GUM  47232  // sGum [512] f32 = 2048
#define OFF_BID  49280  // i32[64]
#define OFF_LIST 49536  // i32[64] slot->pt
#define OFF_CNT  49792  // i32[8]
#define OFF_OFFS 49824  // i32[8]
#define SMEM_SZ  49856

typedef __attribute__((ext_vector_type(8))) _Float16 f16x8;
typedef __attribute__((ext_vector_type(4))) _Float16 f16x4;
typedef __attribute__((ext_vector_type(4))) float f32x4;

#define MFMA(a, b, c) __builtin_amdgcn_mfma_f32_16x16x32_f16((a), (b), (c), 0, 0, 0)

__device__ __forceinline__ unsigned rotl32(unsigned x, int d) {
  return (x << d) | (x >> (32 - d));
}

// JAX threefry2x32, keys (0,42), counter (0, flat), partitionable fold.
__device__ __forceinline__ float gumbel_for(unsigned flat) {
  const unsigned k0 = 0u, k1 = 42u;
  const unsigned ks2 = k0 ^ k1 ^ 0x1BD11BDAu;
  unsigned x0 = 0u + k0;
  unsigned x1 = flat + k1;
#define TF_RND(r) { x0 += x1; x1 = rotl32(x1, r); x1 ^= x0; }
  TF_RND(13) TF_RND(15) TF_RND(26) TF_RND(6)
  x0 += k1;  x1 += ks2 + 1u;
  TF_RND(17) TF_RND(29) TF_RND(16) TF_RND(24)
  x0 += ks2; x1 += k0 + 2u;
  TF_RND(13) TF_RND(15) TF_RND(26) TF_RND(6)
  x0 += k0;  x1 += k1 + 3u;
  TF_RND(17) TF_RND(29) TF_RND(16) TF_RND(24)
  x0 += k1;  x1 += ks2 + 4u;
  TF_RND(13) TF_RND(15) TF_RND(26) TF_RND(6)
  x0 += ks2; x1 += k0 + 5u;
#undef TF_RND
  unsigned bits = x0 ^ x1;
  float u = __uint_as_float((bits >> 9) | 0x3f800000u) - 1.0f;
  return -logf(-logf(u + 1e-20f) + 1e-20f);
}

// ---------------------------------------------------------------------------
// prep: fp32 weights -> fragment-linear f16 (scaled split) in ws  [unchanged]
// ---------------------------------------------------------------------------
__global__ void prep_kernel(const float* __restrict__ W_enc,
                            const float* __restrict__ W_sh,
                            const float* __restrict__ W_r1,
                            _Float16* __restrict__ ws) {
  int idx = blockIdx.x * 256 + threadIdx.x;
  if (idx < 8192) {
    int tile = idx >> 9, r = idx & 511;
    int L = r >> 3, j = r & 7;
    int nt = tile >> 1, kt = tile & 1;
    int k = kt * 32 + (L >> 4) * 8 + j;
    int n = nt * 16 + (L & 15);
    float v = (k < 63) ? W_enc[k * 128 + n] : 0.0f;
    _Float16 h = (_Float16)v;
    ws[WS_ENC_H + idx] = h;
    ws[WS_ENC_L + idx] = (_Float16)((v - (float)h) * 2048.0f);
  } else if (idx < 8192 + 131072) {
    int s = idx - 8192;
    int tile = s >> 9, r = s & 511;
    int L = r >> 3, j = r & 7;
    int e = tile >> 5, nt = (tile >> 2) & 7, kt = tile & 3;
    int k = kt * 32 + (L >> 4) * 8 + j;
    int n = nt * 16 + (L & 15);
    float v = W_sh[e * 16384 + k * 128 + n];
    _Float16 h = (_Float16)v;
    ws[WS_SH_H + s] = h;
    ws[WS_SH_L + s] = (_Float16)((v - (float)h) * 2048.0f);
  } else if (idx < 8192 + 131072 + 81920) {
    int s = idx - (8192 + 131072);
    int tile = s >> 9, r = s & 511;
    int L = r >> 3, j = r & 7;
    int e = tile / 20, rr = tile % 20;
    int nt = rr / 5, kt = rr % 5;
    int k = kt * 32 + (L >> 4) * 8 + j;
    int n = nt * 16 + (L & 15);
    float v = (k < 155) ? W_r1[e * 9920 + k * 64 + n] : 0.0f;
    ws[WS_R1_H + s] = (_Float16)v;
  }
}

// ---------------------------------------------------------------------------
__global__ __launch_bounds__(NTH, 2)
void nerf_moe_kernel(const float* __restrict__ x,
                     const float* __restrict__ b_enc,
                     const float* __restrict__ b_sh,
                     const float* __restrict__ w_sig, const float* __restrict__ b_sig,
                     const float* __restrict__ b_r1,
                     const float* __restrict__ W_r2,  const float* __restrict__ b_r2,
                     const _Float16* __restrict__ wsw,
                     float* __restrict__ out) {
  __shared__ __align__(16) unsigned char smem[SMEM_SZ];
  _Float16* sYh  = (_Float16*)(smem + OFF_YH);
  float*    sH   = (float*)(smem + OFF_YH);
  _Float16* sYl  = (_Float16*)(smem + OFF_B);
  _Float16* sPEh = (_Float16*)(smem + OFF_B);
  _Float16* sPEl = (_Float16*)(smem + OFF_B + 9216);
  _Float16* sSB  = (_Float16*)(smem + OFF_B);
  float*    sRedE = (float*)(smem + OFF_RED);   // [8][4][65]
  float*    sGum = (float*)(smem + OFF_GUM);
  int*      sBid = (int*)(smem + OFF_BID);
  int*      sList = (int*)(smem + OFF_LIST);
  int*      sCnt = (int*)(smem + OFF_CNT);
  int*      sOff = (int*)(smem + OFF_OFFS);

  const int t  = threadIdx.x;
  const int w  = t >> 6;        // wave id 0..3
  const int L  = t & 63;        // lane
  const int q  = L >> 4;        // quad 0..3
  const int c  = L & 15;
  const int n0 = blockIdx.x * PT;

  // ---- phase 0: xyz positional encoding + gumbel precompute ----
  for (int idx = t; idx < PT * 64; idx += NTH) {
    int p = idx >> 6, f = idx & 63;
    const float* xr = x + (size_t)(n0 + p) * 6;
    float v;
    if (f < 3)       v = xr[f];
    else if (f < 33) { int g = f - 3;  v = sinf(xr[g % 3] * (float)(1 << (g / 3))); }
    else if (f < 63) { int g = f - 33; v = cosf(xr[g % 3] * (float)(1 << (g / 3))); }
    else             v = 0.0f;
    _Float16 h = (_Float16)v;
    sPEh[p * 72 + f] = h;
    sPEl[p * 72 + f] = (_Float16)((v - (float)h) * 2048.0f);
  }
  sGum[t]       = gumbel_for((unsigned)(n0 * 8 + t));
  sGum[t + 256] = gumbel_for((unsigned)(n0 * 8 + t + 256));
  __syncthreads();                                   // (1)

  // ---- phase A: Y = relu(PE @ W_enc + b) via MFMA ----
  {
    f16x8 beh[2][2], bel[2][2];
    #pragma unroll
    for (int ntL = 0; ntL < 2; ++ntL)
      #pragma unroll
      for (int kt = 0; kt < 2; ++kt) {
        int tile = (2 * w + ntL) * 2 + kt;
        beh[ntL][kt] = *(const f16x8*)(wsw + WS_ENC_H + tile * 512 + L * 8);
        bel[ntL][kt] = *(const f16x8*)(wsw + WS_ENC_L + tile * 512 + L * 8);
      }
    f16x8 pah[4][2], pal[4][2];
    #pragma unroll
    for (int mt = 0; mt < 4; ++mt)
      #pragma unroll
      for (int kt = 0; kt < 2; ++kt) {
        int off = (mt * 16 + c) * 72 + kt * 32 + q * 8;
        pah[mt][kt] = *(const f16x8*)(sPEh + off);
        pal[mt][kt] = *(const f16x8*)(sPEl + off);
      }
    f32x4 a1[4][2], a2[4][2];
    #pragma unroll
    for (int mt = 0; mt < 4; ++mt)
      #pragma unroll
      for (int ntL = 0; ntL < 2; ++ntL) { a1[mt][ntL] = (f32x4)0.0f; a2[mt][ntL] = (f32x4)0.0f; }
    #pragma unroll
    for (int kt = 0; kt < 2; ++kt)
      #pragma unroll
      for (int mt = 0; mt < 4; ++mt)
        #pragma unroll
        for (int ntL = 0; ntL < 2; ++ntL) {
          a1[mt][ntL] = MFMA(pah[mt][kt], beh[ntL][kt], a1[mt][ntL]);
          a2[mt][ntL] = MFMA(pah[mt][kt], bel[ntL][kt], a2[mt][ntL]);
          a2[mt][ntL] = MFMA(pal[mt][kt], beh[ntL][kt], a2[mt][ntL]);
        }
    __syncthreads();                                 // (2) sPE reads done -> sYl writable
    float bb0 = b_enc[(2 * w) * 16 + c];
    float bb1 = b_enc[(2 * w + 1) * 16 + c];
    #pragma unroll
    for (int mt = 0; mt < 4; ++mt)
      #pragma unroll
      for (int ntL = 0; ntL < 2; ++ntL) {
        float bb = ntL ? bb1 : bb0;
        int col = (2 * w + ntL) * 16 + c;
        #pragma unroll
        for (int r = 0; r < 4; ++r) {
          float v = fmaxf(a1[mt][ntL][r] + a2[mt][ntL][r] * INV2048 + bb, 0.0f);
          int row = mt * 16 + q * 4 + r;
          _Float16 h = (_Float16)v;
          sYh[row * 136 + col] = h;
          sYl[row * 136 + col] = (_Float16)((v - (float)h) * 2048.0f);
        }
      }
  }
  __syncthreads();                                   // (3)

  // hoist Y hi frags (64 VGPR); lo re-read from sYl per use
  f16x8 Ah[4][4];
  #pragma unroll
  for (int nt = 0; nt < 4; ++nt)
    #pragma unroll
    for (int kt = 0; kt < 4; ++kt)
      Ah[nt][kt] = *(const f16x8*)(sYh + (nt * 16 + c) * 136 + kt * 32 + q * 8);
  const f32x4 wsv0 = *(const f32x4*)(w_sig + (2 * w) * 16 + q * 4);
  const f32x4 wsv1 = *(const f32x4*)(w_sig + (2 * w + 1) * 16 + q * 4);

  // ---- pass 1: 8 experts, transposed S^T, ZERO barriers ----
  #pragma unroll 1
  for (int e = 0; e < 8; ++e) {
    float psum[4] = {0.f, 0.f, 0.f, 0.f};
    #pragma unroll
    for (int i = 0; i < 2; ++i) {                    // h-tile 2w+i
      f32x4 a1[4], a2[4];
      #pragma unroll
      for (int nt = 0; nt < 4; ++nt) { a1[nt] = (f32x4)0.0f; a2[nt] = (f32x4)0.0f; }
      #pragma unroll
      for (int kt = 0; kt < 4; ++kt) {
        int tile = (e * 8 + 2 * w + i) * 4 + kt;
        f16x8 bh = *(const f16x8*)(wsw + WS_SH_H + tile * 512 + L * 8);
        f16x8 bl = *(const f16x8*)(wsw + WS_SH_L + tile * 512 + L * 8);
        #pragma unroll
        for (int nt = 0; nt < 4; ++nt) {
          f16x8 al = *(const f16x8*)(sYl + (nt * 16 + c) * 136 + kt * 32 + q * 8);
          a1[nt] = MFMA(bh, Ah[nt][kt], a1[nt]);
          a2[nt] = MFMA(bl, Ah[nt][kt], a2[nt]);
          a2[nt] = MFMA(bh, al, a2[nt]);
        }
      }
      f32x4 bb = *(const f32x4*)(b_sh + e * 128 + (2 * w + i) * 16 + q * 4);
      f32x4 wv = i ? wsv1 : wsv0;
      #pragma unroll
      for (int nt = 0; nt < 4; ++nt)
        #pragma unroll
        for (int r = 0; r < 4; ++r) {
          float s = fmaxf(fmaf(a2[nt][r], INV2048, a1[nt][r]) + bb[r], 0.0f);
          psum[nt] = fmaf(s, wv[r], psum[nt]);
        }
    }
    // quad-reduction in-register: sum over q via shfl_xor(16/32)
    #pragma unroll
    for (int nt = 0; nt < 4; ++nt) {
      float v = psum[nt];
      v += __shfl_xor(v, 16);
      v += __shfl_xor(v, 32);
      psum[nt] = v;
    }
    if (q == 0) {
      #pragma unroll
      for (int nt = 0; nt < 4; ++nt)
        sRedE[e * 260 + w * 65 + nt * 16 + c] = psum[nt];
    }
  }
  __syncthreads();                                   // (4) — the ONLY pass-1 barrier

  // ---- argmax: one pass, t<64 ----
  if (t < PT) {
    float best = 0.0f, bsig = 0.0f;
    int bide = 0;
    const float bs = b_sig[0];
    #pragma unroll
    for (int e = 0; e < 8; ++e) {
      const float* rp = sRedE + e * 260 + t;
      float s = (rp[0] + rp[65]) + (rp[130] + rp[195]);
      float dotv = s + bs;
      float sig = fmaxf(dotv, 0.0f) + log1pf(expf(-fabsf(dotv)));
      float z = logf(sig + 1e-10f) / 0.166667f;
      float score = z + sGum[t * 8 + e];
      if (e == 0 || score > best) { best = score; bsig = sig; bide = e; }
    }
    sBid[t] = bide;
    out[(size_t)(n0 + t) * 4 + 3] = bsig;
  }
  __syncthreads();                                   // (5)

  // ---- bucket lists ----
  if (t < 8) {
    int cnt = 0;
    for (int p = 0; p < PT; ++p) cnt += (sBid[p] == t);
    sCnt[t] = cnt;
  }
  __syncthreads();                                   // (6)
  if (t < 8) {
    int off = 0;
    for (int i = 0; i < t; ++i) off += sCnt[i];
    sOff[t] = off;
    int k = off;
    for (int p = 0; p < PT; ++p) if (sBid[p] == t) sList[k++] = p;
  }
  __syncthreads();                                   // (7)

  // ---- pass 2a: viewdir PE into sSB + winner S recompute (transposed) ----
  for (int idx = t; idx < PT * 32; idx += NTH) {
    int s = idx >> 5, cc = idx & 31;
    int pt = sList[s];
    const float* xr = x + (size_t)(n0 + pt) * 6 + 3;
    float v;
    if (cc < 3)       v = xr[cc];
    else if (cc < 15) { int g = cc - 3;  v = sinf(xr[g % 3] * (float)(1 << (g / 3))); }
    else if (cc < 27) { int g = cc - 15; v = cosf(xr[g % 3] * (float)(1 << (g / 3))); }
    else              v = 0.0f;
    sSB[s * 168 + 128 + cc] = (_Float16)v;
  }
  #pragma unroll 1
  for (int ei = 0; ei < 2; ++ei) {
    int e = 2 * w + ei;
    int cnt = sCnt[e], off = sOff[e];
    for (int base = 0; base < cnt; base += 16) {
      int sidx = base + c; if (sidx >= cnt) sidx = cnt - 1;
      int pt = sList[off + sidx];
      f16x8 yb[4];
      #pragma unroll
      for (int kt = 0; kt < 4; ++kt)
        yb[kt] = *(const f16x8*)(sYh + pt * 136 + kt * 32 + q * 8);
      f32x4 acc[8];
      #pragma unroll
      for (int jt = 0; jt < 8; ++jt) acc[jt] = (f32x4)0.0f;
      #pragma unroll
      for (int jt = 0; jt < 8; ++jt)
        #pragma unroll
        for (int kt = 0; kt < 4; ++kt) {
          f16x8 a = *(const f16x8*)(wsw + WS_SH_H + ((e * 8 + jt) * 4 + kt) * 512 + L * 8);
          acc[jt] = MFMA(a, yb[kt], acc[jt]);
        }
      bool wr = (base + c) < cnt;
      int slot = off + base + c;
      #pragma unroll
      for (int jt = 0; jt < 8; ++jt) {
        f32x4 bb = *(const f32x4*)(b_sh + e * 128 + jt * 16 + q * 4);
        f16x4 v;
        #pragma unroll
        for (int r = 0; r < 4; ++r)
          v[r] = (_Float16)fmaxf(acc[jt][r] + bb[r], 0.0f);
        if (wr) *(f16x4*)(sSB + slot * 168 + jt * 16 + q * 4) = v;
      }
    }
  }
  __syncthreads();                                   // (8) sYh dead -> sH writable

  // ---- pass 2b: rgb layer 1 via MFMA ([S;vd] @ W_r1) ----
  #pragma unroll 1
  for (int ei = 0; ei < 2; ++ei) {
    int e = 2 * w + ei;
    int cnt = sCnt[e], off = sOff[e];
    for (int base = 0; base < cnt; base += 16) {
      int sidx = base + c; if (sidx >= cnt) sidx = cnt - 1;
      int slot = off + sidx;
      f16x8 ag[5];
      #pragma unroll
      for (int kt = 0; kt < 5; ++kt)
        ag[kt] = *(const f16x8*)(sSB + slot * 168 + kt * 32 + q * 8);
      f32x4 hacc[4];
      #pragma unroll
      for (int nt = 0; nt < 4; ++nt) hacc[nt] = (f32x4)0.0f;
      #pragma unroll
      for (int nt = 0; nt < 4; ++nt)
        #pragma unroll
        for (int kt = 0; kt < 5; ++kt) {
          f16x8 bf = *(const f16x8*)(wsw + WS_R1_H + ((e * 4 + nt) * 5 + kt) * 512 + L * 8);
          hacc[nt] = MFMA(ag[kt], bf, hacc[nt]);
        }
      #pragma unroll
      for (int nt = 0; nt < 4; ++nt) {
        float bb = b_r1[e * 64 + nt * 16 + c];
        #pragma unroll
        for (int r = 0; r < 4; ++r) {
          int m = q * 4 + r;
          if (base + m < cnt)
            sH[(off + base + m) * 68 + nt * 16 + c] = fmaxf(hacc[nt][r] + bb, 0.0f);
        }
      }
    }
  }
  __syncthreads();                                   // (9)

  // ---- layer 2: rgb = sigmoid(h @ W_r2 + b) ----
  if (t < 192) {
    int s = t / 3, o = t - s * 3;
    int pt = sList[s];
    int e = sBid[pt];
    float a = b_r2[e * 3 + o];
    const float* w2 = W_r2 + e * 192 + o;
    #pragma unroll
    for (int jj = 0; jj < 64; jj += 4) {
      f32x4 h4 = *(const f32x4*)(sH + s * 68 + jj);
      a = fmaf(h4.x, w2[jj * 3], a);
      a = fmaf(h4.y, w2[jj * 3 + 3], a);
      a = fmaf(h4.z, w2[jj * 3 + 6], a);
      a = fmaf(h4.w, w2[jj * 3 + 9], a);
    }
    out[(size_t)(n0 + pt) * 4 + o] = 1.0f / (1.0f + expf(-a));
  }
}

extern "C" void kernel_launch(void* const* d_in, const int* in_sizes, int n_in,
                              void* d_out, int out_size, void* d_ws, size_t ws_size,
                              hipStream_t stream) {
  (void)in_sizes; (void)n_in; (void)ws_size; (void)out_size;
  const float* x     = (const float*)d_in[0];
  const float* W_enc = (const float*)d_in[1];
  const float* b_enc = (const float*)d_in[2];
  const float* W_sh  = (const float*)d_in[3];
  const float* b_sh  = (const float*)d_in[4];
  const float* w_sig = (const float*)d_in[5];
  const float* b_sig = (const float*)d_in[6];
  const float* W_r1  = (const float*)d_in[7];
  const float* b_r1  = (const float*)d_in[8];
  const float* W_r2  = (const float*)d_in[9];
  const float* b_r2  = (const float*)d_in[10];
  _Float16* ws = (_Float16*)d_ws;     // needs 720896 B
  float* outp = (float*)d_out;
  prep_kernel<<<864, 256, 0, stream>>>(W_enc, W_sh, W_r1, ws);
  nerf_moe_kernel<<<NBLK, NTH, 0, stream>>>(x, b_enc, b_sh, w_sig, b_sig,
                                            b_r1, W_r2, b_r2, ws, outp);
}

// Round 6
// 278.540 us; speedup vs baseline: 1.8740x; 1.0024x over previous
//
#include <hip/hip_runtime.h>
#include <hip/hip_bf16.h>

// ---------------------------------------------------------------------------
// GumbelNeRF fused kernel, round 6: LDS -> 47104 B for 3 blocks/CU.
//
// Key finding (R2..R5 occupancy): usable LDS/CU on MI355X is ~144-147 KB,
// not 160 KB. 3-block threshold proven between 47104 B (R4: occ 29.7%)
// and 50176 B (R5: occ 21.6%). This round ONLY shrinks LDS to exactly
// 47104 via overlays — compute structure is byte-identical to round 5:
//  - sGum (2048 B) overlaid at region-B tail (OFF_B+18432): sPE ends
//    there; sSB overwrites it only in pass 2a, after argmax read it.
//  - sRedE stride 65 -> 64 (pad was unnecessary: argmax reads column t ->
//    banks t%32 = 2-way free; writes hit 16 distinct banks). 8192 B.
//  - sBid/sList/sCnt/sOff overlaid into sRedE region (sBid store is
//    program-ordered after the same wave's sRedE loads; others written
//    after barrier 5 when sRedE is dead).
// Sigma numerics unchanged: f16 3-product split (hi + lo/2048), fp32
// accumulate, threefry gumbel (passing since round 2).
// ---------------------------------------------------------------------------

#define NPTS 131072
#define PT 64
#define NTH 256
#define NBLK (NPTS / PT)
#define INV2048 (1.0f / 2048.0f)

// ws sections (f16 element offsets) — identical to rounds 2-5
#define WS_ENC_H 0
#define WS_ENC_L 8192
#define WS_SH_H  16384
#define WS_SH_L  147456
#define WS_R1_H  278528

// LDS byte offsets, total 47104 (= 46 KiB exactly; 3 blocks/CU)
#define OFF_YH   0      // sYh [64][136] f16 = 17408 ; pass2b+: sH [64][68] f32
#define OFF_B    17408  // 21504 B: sPEh[64][72](9216)+sPEl(9216)+sGum(2048) | sYl[64][136] | sSB[64][168] f16
#define OFF_GUM  35840  // = OFF_B + 18432 (dead tail of region B until pass 2a)
#define OFF_RED  38912  // sRedE [8][4][64] f32 = 8192 ; smalls overlaid below
#define OFF_LIST (OFF_RED + 0)     // i32[64] (written after barrier 6)
#define OFF_CNT  (OFF_RED + 256)   // i32[8]  (written after barrier 5)
#define OFF_OFFS (OFF_RED + 288)   // i32[8]
#define OFF_BID  (OFF_RED + 320)   // i32[64] (store ordered after sRedE loads)
#define SMEM_SZ  47104

typedef __attribute__((ext_vector_type(8))) _Float16 f16x8;
typedef __attribute__((ext_vector_type(4))) _Float16 f16x4;
typedef __attribute__((ext_vector_type(4))) float f32x4;

#define MFMA(a, b, c) __builtin_amdgcn_mfma_f32_16x16x32_f16((a), (b), (c), 0, 0, 0)

__device__ __forceinline__ unsigned rotl32(unsigned x, int d) {
  return (x << d) | (x >> (32 - d));
}

// JAX threefry2x32, keys (0,42), counter (0, flat), partitionable fold.
__device__ __forceinline__ float gumbel_for(unsigned flat) {
  const unsigned k0 = 0u, k1 = 42u;
  const unsigned ks2 = k0 ^ k1 ^ 0x1BD11BDAu;
  unsigned x0 = 0u + k0;
  unsigned x1 = flat + k1;
#define TF_RND(r) { x0 += x1; x1 = rotl32(x1, r); x1 ^= x0; }
  TF_RND(13) TF_RND(15) TF_RND(26) TF_RND(6)
  x0 += k1;  x1 += ks2 + 1u;
  TF_RND(17) TF_RND(29) TF_RND(16) TF_RND(24)
  x0 += ks2; x1 += k0 + 2u;
  TF_RND(13) TF_RND(15) TF_RND(26) TF_RND(6)
  x0 += k0;  x1 += k1 + 3u;
  TF_RND(17) TF_RND(29) TF_RND(16) TF_RND(24)
  x0 += k1;  x1 += ks2 + 4u;
  TF_RND(13) TF_RND(15) TF_RND(26) TF_RND(6)
  x0 += ks2; x1 += k0 + 5u;
#undef TF_RND
  unsigned bits = x0 ^ x1;
  float u = __uint_as_float((bits >> 9) | 0x3f800000u) - 1.0f;
  return -logf(-logf(u + 1e-20f) + 1e-20f);
}

// ---------------------------------------------------------------------------
// prep: fp32 weights -> fragment-linear f16 (scaled split) in ws  [unchanged]
// ---------------------------------------------------------------------------
__global__ void prep_kernel(const float* __restrict__ W_enc,
                            const float* __restrict__ W_sh,
                            const float* __restrict__ W_r1,
                            _Float16* __restrict__ ws) {
  int idx = blockIdx.x * 256 + threadIdx.x;
  if (idx < 8192) {
    int tile = idx >> 9, r = idx & 511;
    int L = r >> 3, j = r & 7;
    int nt = tile >> 1, kt = tile & 1;
    int k = kt * 32 + (L >> 4) * 8 + j;
    int n = nt * 16 + (L & 15);
    float v = (k < 63) ? W_enc[k * 128 + n] : 0.0f;
    _Float16 h = (_Float16)v;
    ws[WS_ENC_H + idx] = h;
    ws[WS_ENC_L + idx] = (_Float16)((v - (float)h) * 2048.0f);
  } else if (idx < 8192 + 131072) {
    int s = idx - 8192;
    int tile = s >> 9, r = s & 511;
    int L = r >> 3, j = r & 7;
    int e = tile >> 5, nt = (tile >> 2) & 7, kt = tile & 3;
    int k = kt * 32 + (L >> 4) * 8 + j;
    int n = nt * 16 + (L & 15);
    float v = W_sh[e * 16384 + k * 128 + n];
    _Float16 h = (_Float16)v;
    ws[WS_SH_H + s] = h;
    ws[WS_SH_L + s] = (_Float16)((v - (float)h) * 2048.0f);
  } else if (idx < 8192 + 131072 + 81920) {
    int s = idx - (8192 + 131072);
    int tile = s >> 9, r = s & 511;
    int L = r >> 3, j = r & 7;
    int e = tile / 20, rr = tile % 20;
    int nt = rr / 5, kt = rr % 5;
    int k = kt * 32 + (L >> 4) * 8 + j;
    int n = nt * 16 + (L & 15);
    float v = (k < 155) ? W_r1[e * 9920 + k * 64 + n] : 0.0f;
    ws[WS_R1_H + s] = (_Float16)v;
  }
}

// ---------------------------------------------------------------------------
__global__ __launch_bounds__(NTH, 2)
void nerf_moe_kernel(const float* __restrict__ x,
                     const float* __restrict__ b_enc,
                     const float* __restrict__ b_sh,
                     const float* __restrict__ w_sig, const float* __restrict__ b_sig,
                     const float* __restrict__ b_r1,
                     const float* __restrict__ W_r2,  const float* __restrict__ b_r2,
                     const _Float16* __restrict__ wsw,
                     float* __restrict__ out) {
  __shared__ __align__(16) unsigned char smem[SMEM_SZ];
  _Float16* sYh  = (_Float16*)(smem + OFF_YH);
  float*    sH   = (float*)(smem + OFF_YH);
  _Float16* sYl  = (_Float16*)(smem + OFF_B);
  _Float16* sPEh = (_Float16*)(smem + OFF_B);
  _Float16* sPEl = (_Float16*)(smem + OFF_B + 9216);
  _Float16* sSB  = (_Float16*)(smem + OFF_B);
  float*    sRedE = (float*)(smem + OFF_RED);   // [8][4][64]
  float*    sGum = (float*)(smem + OFF_GUM);
  int*      sBid = (int*)(smem + OFF_BID);
  int*      sList = (int*)(smem + OFF_LIST);
  int*      sCnt = (int*)(smem + OFF_CNT);
  int*      sOff = (int*)(smem + OFF_OFFS);

  const int t  = threadIdx.x;
  const int w  = t >> 6;        // wave id 0..3
  const int L  = t & 63;        // lane
  const int q  = L >> 4;        // quad 0..3
  const int c  = L & 15;
  const int n0 = blockIdx.x * PT;

  // ---- phase 0: xyz positional encoding + gumbel precompute ----
  for (int idx = t; idx < PT * 64; idx += NTH) {
    int p = idx >> 6, f = idx & 63;
    const float* xr = x + (size_t)(n0 + p) * 6;
    float v;
    if (f < 3)       v = xr[f];
    else if (f < 33) { int g = f - 3;  v = sinf(xr[g % 3] * (float)(1 << (g / 3))); }
    else if (f < 63) { int g = f - 33; v = cosf(xr[g % 3] * (float)(1 << (g / 3))); }
    else             v = 0.0f;
    _Float16 h = (_Float16)v;
    sPEh[p * 72 + f] = h;
    sPEl[p * 72 + f] = (_Float16)((v - (float)h) * 2048.0f);
  }
  sGum[t]       = gumbel_for((unsigned)(n0 * 8 + t));
  sGum[t + 256] = gumbel_for((unsigned)(n0 * 8 + t + 256));
  __syncthreads();                                   // (1)

  // ---- phase A: Y = relu(PE @ W_enc + b) via MFMA ----
  {
    f16x8 beh[2][2], bel[2][2];
    #pragma unroll
    for (int ntL = 0; ntL < 2; ++ntL)
      #pragma unroll
      for (int kt = 0; kt < 2; ++kt) {
        int tile = (2 * w + ntL) * 2 + kt;
        beh[ntL][kt] = *(const f16x8*)(wsw + WS_ENC_H + tile * 512 + L * 8);
        bel[ntL][kt] = *(const f16x8*)(wsw + WS_ENC_L + tile * 512 + L * 8);
      }
    f16x8 pah[4][2], pal[4][2];
    #pragma unroll
    for (int mt = 0; mt < 4; ++mt)
      #pragma unroll
      for (int kt = 0; kt < 2; ++kt) {
        int off = (mt * 16 + c) * 72 + kt * 32 + q * 8;
        pah[mt][kt] = *(const f16x8*)(sPEh + off);
        pal[mt][kt] = *(const f16x8*)(sPEl + off);
      }
    f32x4 a1[4][2], a2[4][2];
    #pragma unroll
    for (int mt = 0; mt < 4; ++mt)
      #pragma unroll
      for (int ntL = 0; ntL < 2; ++ntL) { a1[mt][ntL] = (f32x4)0.0f; a2[mt][ntL] = (f32x4)0.0f; }
    #pragma unroll
    for (int kt = 0; kt < 2; ++kt)
      #pragma unroll
      for (int mt = 0; mt < 4; ++mt)
        #pragma unroll
        for (int ntL = 0; ntL < 2; ++ntL) {
          a1[mt][ntL] = MFMA(pah[mt][kt], beh[ntL][kt], a1[mt][ntL]);
          a2[mt][ntL] = MFMA(pah[mt][kt], bel[ntL][kt], a2[mt][ntL]);
          a2[mt][ntL] = MFMA(pal[mt][kt], beh[ntL][kt], a2[mt][ntL]);
        }
    __syncthreads();                                 // (2) sPE reads done -> sYl writable
    float bb0 = b_enc[(2 * w) * 16 + c];
    float bb1 = b_enc[(2 * w + 1) * 16 + c];
    #pragma unroll
    for (int mt = 0; mt < 4; ++mt)
      #pragma unroll
      for (int ntL = 0; ntL < 2; ++ntL) {
        float bb = ntL ? bb1 : bb0;
        int col = (2 * w + ntL) * 16 + c;
        #pragma unroll
        for (int r = 0; r < 4; ++r) {
          float v = fmaxf(a1[mt][ntL][r] + a2[mt][ntL][r] * INV2048 + bb, 0.0f);
          int row = mt * 16 + q * 4 + r;
          _Float16 h = (_Float16)v;
          sYh[row * 136 + col] = h;
          sYl[row * 136 + col] = (_Float16)((v - (float)h) * 2048.0f);
        }
      }
  }
  __syncthreads();                                   // (3)

  // hoist Y hi frags (64 VGPR); lo re-read from sYl per use
  f16x8 Ah[4][4];
  #pragma unroll
  for (int nt = 0; nt < 4; ++nt)
    #pragma unroll
    for (int kt = 0; kt < 4; ++kt)
      Ah[nt][kt] = *(const f16x8*)(sYh + (nt * 16 + c) * 136 + kt * 32 + q * 8);
  const f32x4 wsv0 = *(const f32x4*)(w_sig + (2 * w) * 16 + q * 4);
  const f32x4 wsv1 = *(const f32x4*)(w_sig + (2 * w + 1) * 16 + q * 4);

  // ---- pass 1: 8 experts, transposed S^T, ZERO barriers ----
  #pragma unroll 1
  for (int e = 0; e < 8; ++e) {
    float psum[4] = {0.f, 0.f, 0.f, 0.f};
    #pragma unroll
    for (int i = 0; i < 2; ++i) {                    // h-tile 2w+i
      f32x4 a1[4], a2[4];
      #pragma unroll
      for (int nt = 0; nt < 4; ++nt) { a1[nt] = (f32x4)0.0f; a2[nt] = (f32x4)0.0f; }
      #pragma unroll
      for (int kt = 0; kt < 4; ++kt) {
        int tile = (e * 8 + 2 * w + i) * 4 + kt;
        f16x8 bh = *(const f16x8*)(wsw + WS_SH_H + tile * 512 + L * 8);
        f16x8 bl = *(const f16x8*)(wsw + WS_SH_L + tile * 512 + L * 8);
        #pragma unroll
        for (int nt = 0; nt < 4; ++nt) {
          f16x8 al = *(const f16x8*)(sYl + (nt * 16 + c) * 136 + kt * 32 + q * 8);
          a1[nt] = MFMA(bh, Ah[nt][kt], a1[nt]);
          a2[nt] = MFMA(bl, Ah[nt][kt], a2[nt]);
          a2[nt] = MFMA(bh, al, a2[nt]);
        }
      }
      f32x4 bb = *(const f32x4*)(b_sh + e * 128 + (2 * w + i) * 16 + q * 4);
      f32x4 wv = i ? wsv1 : wsv0;
      #pragma unroll
      for (int nt = 0; nt < 4; ++nt)
        #pragma unroll
        for (int r = 0; r < 4; ++r) {
          float s = fmaxf(fmaf(a2[nt][r], INV2048, a1[nt][r]) + bb[r], 0.0f);
          psum[nt] = fmaf(s, wv[r], psum[nt]);
        }
    }
    // quad-reduction in-register: sum over q via shfl_xor(16/32)
    #pragma unroll
    for (int nt = 0; nt < 4; ++nt) {
      float v = psum[nt];
      v += __shfl_xor(v, 16);
      v += __shfl_xor(v, 32);
      psum[nt] = v;
    }
    if (q == 0) {
      #pragma unroll
      for (int nt = 0; nt < 4; ++nt)
        sRedE[e * 256 + w * 64 + nt * 16 + c] = psum[nt];
    }
  }
  __syncthreads();                                   // (4) — the ONLY pass-1 barrier

  // ---- argmax: one pass, t<64 ----
  if (t < PT) {
    float best = 0.0f, bsig = 0.0f;
    int bide = 0;
    const float bs = b_sig[0];
    #pragma unroll
    for (int e = 0; e < 8; ++e) {
      const float* rp = sRedE + e * 256 + t;
      float s = (rp[0] + rp[64]) + (rp[128] + rp[192]);
      float dotv = s + bs;
      float sig = fmaxf(dotv, 0.0f) + log1pf(expf(-fabsf(dotv)));
      float z = logf(sig + 1e-10f) / 0.166667f;
      float score = z + sGum[t * 8 + e];
      if (e == 0 || score > best) { best = score; bsig = sig; bide = e; }
    }
    sBid[t] = bide;   // overlaid in sRedE region: store is ordered after
                      // this wave's sRedE loads (same-wave program order)
    out[(size_t)(n0 + t) * 4 + 3] = bsig;
  }
  __syncthreads();                                   // (5)

  // ---- bucket lists (sList/sCnt/sOff overlaid in dead sRedE) ----
  if (t < 8) {
    int cnt = 0;
    for (int p = 0; p < PT; ++p) cnt += (sBid[p] == t);
    sCnt[t] = cnt;
  }
  __syncthreads();                                   // (6)
  if (t < 8) {
    int off = 0;
    for (int i = 0; i < t; ++i) off += sCnt[i];
    sOff[t] = off;
    int k = off;
    for (int p = 0; p < PT; ++p) if (sBid[p] == t) sList[k++] = p;
  }
  __syncthreads();                                   // (7)

  // ---- pass 2a: viewdir PE into sSB + winner S recompute (transposed) ----
  for (int idx = t; idx < PT * 32; idx += NTH) {
    int s = idx >> 5, cc = idx & 31;
    int pt = sList[s];
    const float* xr = x + (size_t)(n0 + pt) * 6 + 3;
    float v;
    if (cc < 3)       v = xr[cc];
    else if (cc < 15) { int g = cc - 3;  v = sinf(xr[g % 3] * (float)(1 << (g / 3))); }
    else if (cc < 27) { int g = cc - 15; v = cosf(xr[g % 3] * (float)(1 << (g / 3))); }
    else              v = 0.0f;
    sSB[s * 168 + 128 + cc] = (_Float16)v;
  }
  #pragma unroll 1
  for (int ei = 0; ei < 2; ++ei) {
    int e = 2 * w + ei;
    int cnt = sCnt[e], off = sOff[e];
    for (int base = 0; base < cnt; base += 16) {
      int sidx = base + c; if (sidx >= cnt) sidx = cnt - 1;
      int pt = sList[off + sidx];
      f16x8 yb[4];
      #pragma unroll
      for (int kt = 0; kt < 4; ++kt)
        yb[kt] = *(const f16x8*)(sYh + pt * 136 + kt * 32 + q * 8);
      f32x4 acc[8];
      #pragma unroll
      for (int jt = 0; jt < 8; ++jt) acc[jt] = (f32x4)0.0f;
      #pragma unroll
      for (int jt = 0; jt < 8; ++jt)
        #pragma unroll
        for (int kt = 0; kt < 4; ++kt) {
          f16x8 a = *(const f16x8*)(wsw + WS_SH_H + ((e * 8 + jt) * 4 + kt) * 512 + L * 8);
          acc[jt] = MFMA(a, yb[kt], acc[jt]);
        }
      bool wr = (base + c) < cnt;
      int slot = off + base + c;
      #pragma unroll
      for (int jt = 0; jt < 8; ++jt) {
        f32x4 bb = *(const f32x4*)(b_sh + e * 128 + jt * 16 + q * 4);
        f16x4 v;
        #pragma unroll
        for (int r = 0; r < 4; ++r)
          v[r] = (_Float16)fmaxf(acc[jt][r] + bb[r], 0.0f);
        if (wr) *(f16x4*)(sSB + slot * 168 + jt * 16 + q * 4) = v;
      }
    }
  }
  __syncthreads();                                   // (8) sYh dead -> sH writable

  // ---- pass 2b: rgb layer 1 via MFMA ([S;vd] @ W_r1) ----
  #pragma unroll 1
  for (int ei = 0; ei < 2; ++ei) {
    int e = 2 * w + ei;
    int cnt = sCnt[e], off = sOff[e];
    for (int base = 0; base < cnt; base += 16) {
      int sidx = base + c; if (sidx >= cnt) sidx = cnt - 1;
      int slot = off + sidx;
      f16x8 ag[5];
      #pragma unroll
      for (int kt = 0; kt < 5; ++kt)
        ag[kt] = *(const f16x8*)(sSB + slot * 168 + kt * 32 + q * 8);
      f32x4 hacc[4];
      #pragma unroll
      for (int nt = 0; nt < 4; ++nt) hacc[nt] = (f32x4)0.0f;
      #pragma unroll
      for (int nt = 0; nt < 4; ++nt)
        #pragma unroll
        for (int kt = 0; kt < 5; ++kt) {
          f16x8 bf = *(const f16x8*)(wsw + WS_R1_H + ((e * 4 + nt) * 5 + kt) * 512 + L * 8);
          hacc[nt] = MFMA(ag[kt], bf, hacc[nt]);
        }
      #pragma unroll
      for (int nt = 0; nt < 4; ++nt) {
        float bb = b_r1[e * 64 + nt * 16 + c];
        #pragma unroll
        for (int r = 0; r < 4; ++r) {
          int m = q * 4 + r;
          if (base + m < cnt)
            sH[(off + base + m) * 68 + nt * 16 + c] = fmaxf(hacc[nt][r] + bb, 0.0f);
        }
      }
    }
  }
  __syncthreads();                                   // (9)

  // ---- layer 2: rgb = sigmoid(h @ W_r2 + b) ----
  if (t < 192) {
    int s = t / 3, o = t - s * 3;
    int pt = sList[s];
    int e = sBid[pt];
    float a = b_r2[e * 3 + o];
    const float* w2 = W_r2 + e * 192 + o;
    #pragma unroll
    for (int jj = 0; jj < 64; jj += 4) {
      f32x4 h4 = *(const f32x4*)(sH + s * 68 + jj);
      a = fmaf(h4.x, w2[jj * 3], a);
      a = fmaf(h4.y, w2[jj * 3 + 3], a);
      a = fmaf(h4.z, w2[jj * 3 + 6], a);
      a = fmaf(h4.w, w2[jj * 3 + 9], a);
    }
    out[(size_t)(n0 + pt) * 4 + o] = 1.0f / (1.0f + expf(-a));
  }
}

extern "C" void kernel_launch(void* const* d_in, const int* in_sizes, int n_in,
                              void* d_out, int out_size, void* d_ws, size_t ws_size,
                              hipStream_t stream) {
  (void)in_sizes; (void)n_in; (void)ws_size; (void)out_size;
  const float* x     = (const float*)d_in[0];
  const float* W_enc = (const float*)d_in[1];
  const float* b_enc = (const float*)d_in[2];
  const float* W_sh  = (const float*)d_in[3];
  const float* b_sh  = (const float*)d_in[4];
  const float* w_sig = (const float*)d_in[5];
  const float* b_sig = (const float*)d_in[6];
  const float* W_r1  = (const float*)d_in[7];
  const float* b_r1  = (const float*)d_in[8];
  const float* W_r2  = (const float*)d_in[9];
  const float* b_r2  = (const float*)d_in[10];
  _Float16* ws = (_Float16*)d_ws;     // needs 720896 B
  float* outp = (float*)d_out;
  prep_kernel<<<864, 256, 0, stream>>>(W_enc, W_sh, W_r1, ws);
  nerf_moe_kernel<<<NBLK, NTH, 0, stream>>>(x, b_enc, b_sh, w_sig, b_sig,
                                            b_r1, W_r2, b_r2, ws, outp);
}

// Round 7
// 278.263 us; speedup vs baseline: 1.8758x; 1.0010x over previous
//
#include <hip/hip_runtime.h>
#include <hip/hip_bf16.h>

// ---------------------------------------------------------------------------
// GumbelNeRF fused kernel, round 7: software-pipelined pass 1.
//
// R6 post-mortem: per-block 69K cycles vs ~19K MFMA floor; waves stall ~80%
// on un-hidden L2 weight-load latency (loads consumed immediately, unroll-1
// loop blocks cross-iteration hoisting). Fixes:
//  - Pass 1 = fully unrolled 16-step (e,i) pipeline, DOUBLE-BUFFERED weight
//    prefetch in registers (8 tiles + bias per step, alternate buffers).
//  - Distributed argmax: 4 threads/point x 2 experts, gumbel threefry
//    computed in-register (identical flat index/expressions -> bit-identical
//    scores), shfl_xor(1,2) winner tree. sGum LDS eliminated.
//  - sBid/sList/sCnt/sOff live in sSB's row-pad bytes (cols 160..167);
//    LDS stays 47104.
// Sigma numerics unchanged: f16 3-product split (hi + lo/2048), fp32
// accumulate, threefry gumbel (passing since round 2).
// ---------------------------------------------------------------------------

#define NPTS 131072
#define PT 64
#define NTH 256
#define NBLK (NPTS / PT)
#define INV2048 (1.0f / 2048.0f)

// ws sections (f16 element offsets) — identical to rounds 2-6
#define WS_ENC_H 0
#define WS_ENC_L 8192
#define WS_SH_H  16384
#define WS_SH_L  147456
#define WS_R1_H  278528

// LDS byte offsets, total 47104
#define OFF_YH   0      // sYh [64][136] f16 = 17408 ; pass2b+: sH [64][68] f32
#define OFF_B    17408  // 21504 B: sPEh[64][72](9216)+sPEl(9216) | sYl[64][136] | sSB[64][168] f16
#define OFF_RED  38912  // sRedE [8][4][64] f32 = 8192
#define SMEM_SZ  47104

// smalls live in sSB row-pad (cols 160..167 = bytes 320..335 of each 336B row)
#define S_LIST(s) (*(int*)(smem + OFF_B + (s) * 336 + 320))
#define S_BID(p)  (*(int*)(smem + OFF_B + (p) * 336 + 324))
#define S_CNT(e)  (*(int*)(smem + OFF_B + (e) * 336 + 328))
#define S_OFF(e)  (*(int*)(smem + OFF_B + (e) * 336 + 332))

typedef __attribute__((ext_vector_type(8))) _Float16 f16x8;
typedef __attribute__((ext_vector_type(4))) _Float16 f16x4;
typedef __attribute__((ext_vector_type(4))) float f32x4;

#define MFMA(a, b, c) __builtin_amdgcn_mfma_f32_16x16x32_f16((a), (b), (c), 0, 0, 0)

__device__ __forceinline__ unsigned rotl32(unsigned x, int d) {
  return (x << d) | (x >> (32 - d));
}

// JAX threefry2x32, keys (0,42), counter (0, flat), partitionable fold.
__device__ __forceinline__ float gumbel_for(unsigned flat) {
  const unsigned k0 = 0u, k1 = 42u;
  const unsigned ks2 = k0 ^ k1 ^ 0x1BD11BDAu;
  unsigned x0 = 0u + k0;
  unsigned x1 = flat + k1;
#define TF_RND(r) { x0 += x1; x1 = rotl32(x1, r); x1 ^= x0; }
  TF_RND(13) TF_RND(15) TF_RND(26) TF_RND(6)
  x0 += k1;  x1 += ks2 + 1u;
  TF_RND(17) TF_RND(29) TF_RND(16) TF_RND(24)
  x0 += ks2; x1 += k0 + 2u;
  TF_RND(13) TF_RND(15) TF_RND(26) TF_RND(6)
  x0 += k0;  x1 += k1 + 3u;
  TF_RND(17) TF_RND(29) TF_RND(16) TF_RND(24)
  x0 += k1;  x1 += ks2 + 4u;
  TF_RND(13) TF_RND(15) TF_RND(26) TF_RND(6)
  x0 += ks2; x1 += k0 + 5u;
#undef TF_RND
  unsigned bits = x0 ^ x1;
  float u = __uint_as_float((bits >> 9) | 0x3f800000u) - 1.0f;
  return -logf(-logf(u + 1e-20f) + 1e-20f);
}

// ---------------------------------------------------------------------------
// prep: fp32 weights -> fragment-linear f16 (scaled split) in ws  [unchanged]
// ---------------------------------------------------------------------------
__global__ void prep_kernel(const float* __restrict__ W_enc,
                            const float* __restrict__ W_sh,
                            const float* __restrict__ W_r1,
                            _Float16* __restrict__ ws) {
  int idx = blockIdx.x * 256 + threadIdx.x;
  if (idx < 8192) {
    int tile = idx >> 9, r = idx & 511;
    int L = r >> 3, j = r & 7;
    int nt = tile >> 1, kt = tile & 1;
    int k = kt * 32 + (L >> 4) * 8 + j;
    int n = nt * 16 + (L & 15);
    float v = (k < 63) ? W_enc[k * 128 + n] : 0.0f;
    _Float16 h = (_Float16)v;
    ws[WS_ENC_H + idx] = h;
    ws[WS_ENC_L + idx] = (_Float16)((v - (float)h) * 2048.0f);
  } else if (idx < 8192 + 131072) {
    int s = idx - 8192;
    int tile = s >> 9, r = s & 511;
    int L = r >> 3, j = r & 7;
    int e = tile >> 5, nt = (tile >> 2) & 7, kt = tile & 3;
    int k = kt * 32 + (L >> 4) * 8 + j;
    int n = nt * 16 + (L & 15);
    float v = W_sh[e * 16384 + k * 128 + n];
    _Float16 h = (_Float16)v;
    ws[WS_SH_H + s] = h;
    ws[WS_SH_L + s] = (_Float16)((v - (float)h) * 2048.0f);
  } else if (idx < 8192 + 131072 + 81920) {
    int s = idx - (8192 + 131072);
    int tile = s >> 9, r = s & 511;
    int L = r >> 3, j = r & 7;
    int e = tile / 20, rr = tile % 20;
    int nt = rr / 5, kt = rr % 5;
    int k = kt * 32 + (L >> 4) * 8 + j;
    int n = nt * 16 + (L & 15);
    float v = (k < 155) ? W_r1[e * 9920 + k * 64 + n] : 0.0f;
    ws[WS_R1_H + s] = (_Float16)v;
  }
}

// ---------------------------------------------------------------------------
__global__ __launch_bounds__(NTH, 2)
void nerf_moe_kernel(const float* __restrict__ x,
                     const float* __restrict__ b_enc,
                     const float* __restrict__ b_sh,
                     const float* __restrict__ w_sig, const float* __restrict__ b_sig,
                     const float* __restrict__ b_r1,
                     const float* __restrict__ W_r2,  const float* __restrict__ b_r2,
                     const _Float16* __restrict__ wsw,
                     float* __restrict__ out) {
  __shared__ __align__(16) unsigned char smem[SMEM_SZ];
  _Float16* sYh  = (_Float16*)(smem + OFF_YH);
  float*    sH   = (float*)(smem + OFF_YH);
  _Float16* sYl  = (_Float16*)(smem + OFF_B);
  _Float16* sPEh = (_Float16*)(smem + OFF_B);
  _Float16* sPEl = (_Float16*)(smem + OFF_B + 9216);
  _Float16* sSB  = (_Float16*)(smem + OFF_B);
  float*    sRedE = (float*)(smem + OFF_RED);   // [8][4][64]

  const int t  = threadIdx.x;
  const int w  = t >> 6;        // wave id 0..3
  const int L  = t & 63;        // lane
  const int q  = L >> 4;        // quad 0..3
  const int c  = L & 15;
  const int n0 = blockIdx.x * PT;

  // ---- phase 0: xyz positional encoding ----
  for (int idx = t; idx < PT * 64; idx += NTH) {
    int p = idx >> 6, f = idx & 63;
    const float* xr = x + (size_t)(n0 + p) * 6;
    float v;
    if (f < 3)       v = xr[f];
    else if (f < 33) { int g = f - 3;  v = sinf(xr[g % 3] * (float)(1 << (g / 3))); }
    else if (f < 63) { int g = f - 33; v = cosf(xr[g % 3] * (float)(1 << (g / 3))); }
    else             v = 0.0f;
    _Float16 h = (_Float16)v;
    sPEh[p * 72 + f] = h;
    sPEl[p * 72 + f] = (_Float16)((v - (float)h) * 2048.0f);
  }
  __syncthreads();                                   // (1)

  // ---- phase A: Y = relu(PE @ W_enc + b) via MFMA ----
  {
    f16x8 beh[2][2], bel[2][2];
    #pragma unroll
    for (int ntL = 0; ntL < 2; ++ntL)
      #pragma unroll
      for (int kt = 0; kt < 2; ++kt) {
        int tile = (2 * w + ntL) * 2 + kt;
        beh[ntL][kt] = *(const f16x8*)(wsw + WS_ENC_H + tile * 512 + L * 8);
        bel[ntL][kt] = *(const f16x8*)(wsw + WS_ENC_L + tile * 512 + L * 8);
      }
    f16x8 pah[4][2], pal[4][2];
    #pragma unroll
    for (int mt = 0; mt < 4; ++mt)
      #pragma unroll
      for (int kt = 0; kt < 2; ++kt) {
        int off = (mt * 16 + c) * 72 + kt * 32 + q * 8;
        pah[mt][kt] = *(const f16x8*)(sPEh + off);
        pal[mt][kt] = *(const f16x8*)(sPEl + off);
      }
    f32x4 a1[4][2], a2[4][2];
    #pragma unroll
    for (int mt = 0; mt < 4; ++mt)
      #pragma unroll
      for (int ntL = 0; ntL < 2; ++ntL) { a1[mt][ntL] = (f32x4)0.0f; a2[mt][ntL] = (f32x4)0.0f; }
    #pragma unroll
    for (int kt = 0; kt < 2; ++kt)
      #pragma unroll
      for (int mt = 0; mt < 4; ++mt)
        #pragma unroll
        for (int ntL = 0; ntL < 2; ++ntL) {
          a1[mt][ntL] = MFMA(pah[mt][kt], beh[ntL][kt], a1[mt][ntL]);
          a2[mt][ntL] = MFMA(pah[mt][kt], bel[ntL][kt], a2[mt][ntL]);
          a2[mt][ntL] = MFMA(pal[mt][kt], beh[ntL][kt], a2[mt][ntL]);
        }
    __syncthreads();                                 // (2) sPE reads done -> sYl writable
    float bb0 = b_enc[(2 * w) * 16 + c];
    float bb1 = b_enc[(2 * w + 1) * 16 + c];
    #pragma unroll
    for (int mt = 0; mt < 4; ++mt)
      #pragma unroll
      for (int ntL = 0; ntL < 2; ++ntL) {
        float bb = ntL ? bb1 : bb0;
        int col = (2 * w + ntL) * 16 + c;
        #pragma unroll
        for (int r = 0; r < 4; ++r) {
          float v = fmaxf(a1[mt][ntL][r] + a2[mt][ntL][r] * INV2048 + bb, 0.0f);
          int row = mt * 16 + q * 4 + r;
          _Float16 h = (_Float16)v;
          sYh[row * 136 + col] = h;
          sYl[row * 136 + col] = (_Float16)((v - (float)h) * 2048.0f);
        }
      }
  }
  __syncthreads();                                   // (3)

  // hoist Y hi frags (64 VGPR); lo re-read from sYl per use
  f16x8 Ah[4][4];
  #pragma unroll
  for (int nt = 0; nt < 4; ++nt)
    #pragma unroll
    for (int kt = 0; kt < 4; ++kt)
      Ah[nt][kt] = *(const f16x8*)(sYh + (nt * 16 + c) * 136 + kt * 32 + q * 8);
  const f32x4 wsv0 = *(const f32x4*)(w_sig + (2 * w) * 16 + q * 4);
  const f32x4 wsv1 = *(const f32x4*)(w_sig + (2 * w + 1) * 16 + q * 4);

  // ---- pass 1: 16-step (e,i) pipeline, double-buffered weight prefetch ----
  float psum[4] = {0.f, 0.f, 0.f, 0.f};

  auto LOADW = [&](int s, f16x8 bh[4], f16x8 bl[4], f32x4& bb) {
    int e = s >> 1, i = s & 1;
    int tbase = (e * 8 + 2 * w + i) * 4;
    #pragma unroll
    for (int kt = 0; kt < 4; ++kt) {
      bh[kt] = *(const f16x8*)(wsw + WS_SH_H + (tbase + kt) * 512 + L * 8);
      bl[kt] = *(const f16x8*)(wsw + WS_SH_L + (tbase + kt) * 512 + L * 8);
    }
    bb = *(const f32x4*)(b_sh + e * 128 + (2 * w + i) * 16 + q * 4);
  };

  auto STEP = [&](int s, const f16x8 bh[4], const f16x8 bl[4], const f32x4& bb) {
    f32x4 a1[4], a2[4];
    #pragma unroll
    for (int nt = 0; nt < 4; ++nt) { a1[nt] = (f32x4)0.0f; a2[nt] = (f32x4)0.0f; }
    #pragma unroll
    for (int kt = 0; kt < 4; ++kt)
      #pragma unroll
      for (int nt = 0; nt < 4; ++nt) {
        f16x8 al = *(const f16x8*)(sYl + (nt * 16 + c) * 136 + kt * 32 + q * 8);
        a1[nt] = MFMA(bh[kt], Ah[nt][kt], a1[nt]);
        a2[nt] = MFMA(bl[kt], Ah[nt][kt], a2[nt]);
        a2[nt] = MFMA(bh[kt], al, a2[nt]);
      }
    f32x4 wv = (s & 1) ? wsv1 : wsv0;
    #pragma unroll
    for (int nt = 0; nt < 4; ++nt)
      #pragma unroll
      for (int r = 0; r < 4; ++r) {
        float sv = fmaxf(fmaf(a2[nt][r], INV2048, a1[nt][r]) + bb[r], 0.0f);
        psum[nt] = fmaf(sv, wv[r], psum[nt]);
      }
    if (s & 1) {                       // end of expert e = s>>1
      int e = s >> 1;
      #pragma unroll
      for (int nt = 0; nt < 4; ++nt) {
        float v = psum[nt];
        v += __shfl_xor(v, 16);
        v += __shfl_xor(v, 32);
        if (q == 0) sRedE[e * 256 + w * 64 + nt * 16 + c] = v;
        psum[nt] = 0.f;
      }
    }
  };

  {
    f16x8 bh0[4], bl0[4], bh1[4], bl1[4];
    f32x4 bb0, bb1;
    LOADW(0, bh0, bl0, bb0);
    #pragma unroll
    for (int s = 0; s < 16; ++s) {
      if ((s & 1) == 0) {
        if (s + 1 < 16) LOADW(s + 1, bh1, bl1, bb1);
        STEP(s, bh0, bl0, bb0);
      } else {
        if (s + 1 < 16) LOADW(s + 1, bh0, bl0, bb0);
        STEP(s, bh1, bl1, bb1);
      }
    }
  }
  __syncthreads();                                   // (4) — only pass-1 barrier

  // ---- argmax: distributed, 4 threads/point x 2 experts, gumbel inline ----
  {
    int pt = t >> 2;
    int eb = (t & 3) * 2;
    float best = -1e30f, bsig = 0.0f;
    int bide = 0;
    const float bs = b_sig[0];
    #pragma unroll
    for (int j = 0; j < 2; ++j) {
      int e = eb + j;
      const float* rp = sRedE + e * 256 + pt;
      float s = (rp[0] + rp[64]) + (rp[128] + rp[192]);
      float dotv = s + bs;
      float sig = fmaxf(dotv, 0.0f) + log1pf(expf(-fabsf(dotv)));
      float z = logf(sig + 1e-10f) / 0.166667f;
      float score = z + gumbel_for((unsigned)((n0 + pt) * 8 + e));
      if (score > best) { best = score; bsig = sig; bide = e; }
    }
    #pragma unroll
    for (int m = 1; m <= 2; m <<= 1) {
      float oS  = __shfl_xor(best, m);
      float oSg = __shfl_xor(bsig, m);
      int   oI  = __shfl_xor(bide, m);
      if (oS > best || (oS == best && oI < bide)) { best = oS; bsig = oSg; bide = oI; }
    }
    if ((t & 3) == 0) {
      S_BID(pt) = bide;                // row-pad slot; sYl dead, sSB not yet
      out[(size_t)(n0 + pt) * 4 + 3] = bsig;
    }
  }
  __syncthreads();                                   // (5)

  // ---- bucket lists ----
  if (t < 8) {
    int cnt = 0;
    for (int p = 0; p < PT; ++p) cnt += (S_BID(p) == t);
    S_CNT(t) = cnt;
  }
  __syncthreads();                                   // (6)
  if (t < 8) {
    int off = 0;
    for (int i = 0; i < t; ++i) off += S_CNT(i);
    S_OFF(t) = off;
    int k = off;
    for (int p = 0; p < PT; ++p) if (S_BID(p) == t) { S_LIST(k) = p; k++; }
  }
  __syncthreads();                                   // (7)

  // ---- pass 2a: viewdir PE into sSB + winner S recompute (transposed) ----
  for (int idx = t; idx < PT * 32; idx += NTH) {
    int s = idx >> 5, cc = idx & 31;
    int pt = S_LIST(s);
    const float* xr = x + (size_t)(n0 + pt) * 6 + 3;
    float v;
    if (cc < 3)       v = xr[cc];
    else if (cc < 15) { int g = cc - 3;  v = sinf(xr[g % 3] * (float)(1 << (g / 3))); }
    else if (cc < 27) { int g = cc - 15; v = cosf(xr[g % 3] * (float)(1 << (g / 3))); }
    else              v = 0.0f;
    sSB[s * 168 + 128 + cc] = (_Float16)v;
  }
  #pragma unroll 1
  for (int ei = 0; ei < 2; ++ei) {
    int e = 2 * w + ei;
    int cnt = S_CNT(e), off = S_OFF(e);
    for (int base = 0; base < cnt; base += 16) {
      int sidx = base + c; if (sidx >= cnt) sidx = cnt - 1;
      int pt = S_LIST(off + sidx);
      f16x8 yb[4];
      #pragma unroll
      for (int kt = 0; kt < 4; ++kt)
        yb[kt] = *(const f16x8*)(sYh + pt * 136 + kt * 32 + q * 8);
      f32x4 acc[8];
      #pragma unroll
      for (int jt = 0; jt < 8; ++jt) acc[jt] = (f32x4)0.0f;
      #pragma unroll
      for (int jt = 0; jt < 8; ++jt)
        #pragma unroll
        for (int kt = 0; kt < 4; ++kt) {
          f16x8 a = *(const f16x8*)(wsw + WS_SH_H + ((e * 8 + jt) * 4 + kt) * 512 + L * 8);
          acc[jt] = MFMA(a, yb[kt], acc[jt]);
        }
      bool wr = (base + c) < cnt;
      int slot = off + base + c;
      #pragma unroll
      for (int jt = 0; jt < 8; ++jt) {
        f32x4 bb = *(const f32x4*)(b_sh + e * 128 + jt * 16 + q * 4);
        f16x4 v;
        #pragma unroll
        for (int r = 0; r < 4; ++r)
          v[r] = (_Float16)fmaxf(acc[jt][r] + bb[r], 0.0f);
        if (wr) *(f16x4*)(sSB + slot * 168 + jt * 16 + q * 4) = v;
      }
    }
  }
  __syncthreads();                                   // (8) sYh dead -> sH writable

  // ---- pass 2b: rgb layer 1 via MFMA ([S;vd] @ W_r1) ----
  #pragma unroll 1
  for (int ei = 0; ei < 2; ++ei) {
    int e = 2 * w + ei;
    int cnt = S_CNT(e), off = S_OFF(e);
    for (int base = 0; base < cnt; base += 16) {
      int sidx = base + c; if (sidx >= cnt) sidx = cnt - 1;
      int slot = off + sidx;
      f16x8 ag[5];
      #pragma unroll
      for (int kt = 0; kt < 5; ++kt)
        ag[kt] = *(const f16x8*)(sSB + slot * 168 + kt * 32 + q * 8);
      f32x4 hacc[4];
      #pragma unroll
      for (int nt = 0; nt < 4; ++nt) hacc[nt] = (f32x4)0.0f;
      #pragma unroll
      for (int nt = 0; nt < 4; ++nt)
        #pragma unroll
        for (int kt = 0; kt < 5; ++kt) {
          f16x8 bf = *(const f16x8*)(wsw + WS_R1_H + ((e * 4 + nt) * 5 + kt) * 512 + L * 8);
          hacc[nt] = MFMA(ag[kt], bf, hacc[nt]);
        }
      #pragma unroll
      for (int nt = 0; nt < 4; ++nt) {
        float bb = b_r1[e * 64 + nt * 16 + c];
        #pragma unroll
        for (int r = 0; r < 4; ++r) {
          int m = q * 4 + r;
          if (base + m < cnt)
            sH[(off + base + m) * 68 + nt * 16 + c] = fmaxf(hacc[nt][r] + bb, 0.0f);
        }
      }
    }
  }
  __syncthreads();                                   // (9)

  // ---- layer 2: rgb = sigmoid(h @ W_r2 + b) ----
  if (t < 192) {
    int s = t / 3, o = t - s * 3;
    int pt = S_LIST(s);
    int e = S_BID(pt);
    float a = b_r2[e * 3 + o];
    const float* w2 = W_r2 + e * 192 + o;
    #pragma unroll
    for (int jj = 0; jj < 64; jj += 4) {
      f32x4 h4 = *(const f32x4*)(sH + s * 68 + jj);
      a = fmaf(h4.x, w2[jj * 3], a);
      a = fmaf(h4.y, w2[jj * 3 + 3], a);
      a = fmaf(h4.z, w2[jj * 3 + 6], a);
      a = fmaf(h4.w, w2[jj * 3 + 9], a);
    }
    out[(size_t)(n0 + pt) * 4 + o] = 1.0f / (1.0f + expf(-a));
  }
}

extern "C" void kernel_launch(void* const* d_in, const int* in_sizes, int n_in,
                              void* d_out, int out_size, void* d_ws, size_t ws_size,
                              hipStream_t stream) {
  (void)in_sizes; (void)n_in; (void)ws_size; (void)out_size;
  const float* x     = (const float*)d_in[0];
  const float* W_enc = (const float*)d_in[1];
  const float* b_enc = (const float*)d_in[2];
  const float* W_sh  = (const float*)d_in[3];
  const float* b_sh  = (const float*)d_in[4];
  const float* w_sig = (const float*)d_in[5];
  const float* b_sig = (const float*)d_in[6];
  const float* W_r1  = (const float*)d_in[7];
  const float* b_r1  = (const float*)d_in[8];
  const float* W_r2  = (const float*)d_in[9];
  const float* b_r2  = (const float*)d_in[10];
  _Float16* ws = (_Float16*)d_ws;     // needs 720896 B
  float* outp = (float*)d_out;
  prep_kernel<<<864, 256, 0, stream>>>(W_enc, W_sh, W_r1, ws);
  nerf_moe_kernel<<<NBLK, NTH, 0, stream>>>(x, b_enc, b_sh, w_sig, b_sig,
                                            b_r1, W_r2, b_r2, ws, outp);
}